// Round 5
// baseline (327.793 us; speedup 1.0000x reference)
//
#include <hip/hip_runtime.h>
#include <cstdint>
#include <cstddef>

typedef unsigned short u16;
typedef __bf16 bf16x8 __attribute__((ext_vector_type(8)));
typedef float f32x4 __attribute__((ext_vector_type(4)));

#define KOFF 27
#define EPSBN 1e-5f

__device__ inline u16 f2bf(float f) {
  unsigned int u = __float_as_uint(f);
  unsigned int r = (u + 0x7FFFu + ((u >> 16) & 1u)) >> 16;  // RNE
  return (u16)r;
}
__device__ inline float bf2f(u16 h) {
  return __uint_as_float(((unsigned int)h) << 16);
}

typedef const __attribute__((address_space(1))) void ga_void;
typedef __attribute__((address_space(3))) void lds_void;
__device__ __forceinline__ void gload_lds16(const void* g, void* l) {
  __builtin_amdgcn_global_load_lds((ga_void*)g, (lds_void*)l, 16, 0, 0);
}

// ---------------- prep kernels ----------------

// cast feats -> bf16; block 0 zeroes stats accumulators + the 128B zero-page
__global__ void k_prep_feats(const float* __restrict__ in, u16* __restrict__ out,
                             float* __restrict__ stats, float* __restrict__ zbuf, int n4) {
  if (blockIdx.x == 0) {
    stats[threadIdx.x] = 0.f;
    if (threadIdx.x < 32) zbuf[threadIdx.x] = 0.f;
  }
  int i = blockIdx.x * 256 + threadIdx.x;
  if (i >= n4) return;
  const float4 v = reinterpret_cast<const float4*>(in)[i];
  ushort4 o;
  o.x = f2bf(v.x); o.y = f2bf(v.y); o.z = f2bf(v.z); o.w = f2bf(v.w);
  reinterpret_cast<ushort4*>(out)[i] = o;
}

// Pack W[k][j][c] (27x64x64 f32) into per-lane MFMA B-fragment order (bf16):
// Wp[ k*4096 + ks*2048 + ct*512 + lane*8 + e ] = W[k][ ks*32 + (lane>>4)*8 + e ][ ct*16 + (lane&15) ]
__global__ void k_prep_w(const float* __restrict__ W, u16* __restrict__ Wp) {
  int tid = blockIdx.x * 256 + threadIdx.x;
  if (tid >= KOFF * 4096) return;
  int k = tid >> 12;
  int rem = tid & 4095;
  int slot = rem >> 3;
  int e = rem & 7;
  int ks = slot >> 8;
  int ct = (slot >> 6) & 3;
  int lane = slot & 63;
  int j = ks * 32 + ((lane >> 4) << 3) + e;
  int c = ct * 16 + (lane & 15);
  Wp[tid] = f2bf(W[(k * 64 + j) * 64 + c]);
}

// Transpose nbr [N,27] -> nbrT [27,N] via LDS tiles (coalesced both sides)
__global__ void k_prep_nbrT(const int* __restrict__ nbr, int* __restrict__ nbrT, int N) {
  __shared__ int L[64 * KOFF];
  const int t = threadIdx.x;
  const int v0 = blockIdx.x * 64;
  const int nv = min(64, N - v0);
  const int cnt = nv * KOFF;
  for (int i = t; i < cnt; i += 256) L[i] = nbr[(size_t)v0 * KOFF + i];
  __syncthreads();
  for (int i = t; i < KOFF * 64; i += 256) {
    int k = i >> 6, j = i & 63;
    if (j < nv) nbrT[(size_t)k * N + v0 + j] = L[j * KOFF + k];
  }
}

// ---------------- conv kernel ----------------
// Block 256 = 4 waves; each wave owns 32 voxels x all 64 output channels.
// A-tiles gathered into wave-PRIVATE LDS double-buffers via global_load_lds
// (per-lane source, zero VGPR staging cost), pipelined one k-offset ahead with
// counted vmcnt(12) — no barriers in the main loop, so prefetch is never drained.
// LDS tile XOR-swizzled via pre-swizzled global source (linear dest + swz read).
// Missing neighbors gather from a 128B zero-page (no exec-mask divergence).
__launch_bounds__(256, 4)
__global__ void k_conv(const u16* __restrict__ F, const u16* __restrict__ Wp,
                       const int* __restrict__ nbrT, const u16* __restrict__ zbuf,
                       float* __restrict__ out, float* __restrict__ stats, int N) {
  __shared__ u16 Ab[4][2][32 * 64];  // 32 KB: [wave][buf][row*64ch]
  __shared__ float sred[4][128];
  const int t = threadIdx.x;
  const int w = t >> 6;
  const int lane = t & 63;

  // bijective XCD-aware block swizzle (m204 form)
  const int nwg = gridDim.x, bid = blockIdx.x;
  const int q = nwg >> 3, r = nwg & 7;
  const int xcd = bid & 7, o = bid >> 3;
  const int wg = (xcd < r ? xcd * (q + 1) : r * (q + 1) + (xcd - r) * q) + o;

  const int vwave = wg * 128 + (w << 5);  // wave's first voxel
  const int lrow = lane >> 3;             // row within 8-row group (0..7)
  const int swz = ((lane & 7) ^ lrow) << 3;  // pre-swizzled source chunk (u16 units)

  f32x4 acc[2][4];
#pragma unroll
  for (int m = 0; m < 2; ++m)
#pragma unroll
    for (int c = 0; c < 4; ++c) acc[m][c] = (f32x4){0.f, 0.f, 0.f, 0.f};

  const u16* zsrc = zbuf + swz;
  u16* const myA = &Ab[w][0][0];

  // ---- prologue ----
  int idv[4];
#pragma unroll
  for (int j = 0; j < 4; ++j) {
    const int v = vwave + (j << 3) + lrow;
    idv[j] = (v < N) ? nbrT[v] : -1;  // k=0 ids
  }
  {
    const u16* s0[4];
#pragma unroll
    for (int j = 0; j < 4; ++j)
      s0[j] = (idv[j] >= 0) ? F + ((size_t)(unsigned)idv[j] << 6) + swz : zsrc;
    // idv <- k=1 (issued before gld_lds so the k=1 wait won't drain the staging)
#pragma unroll
    for (int j = 0; j < 4; ++j) {
      const int v = vwave + (j << 3) + lrow;
      idv[j] = (v < N) ? nbrT[N + v] : -1;
    }
#pragma unroll
    for (int j = 0; j < 4; ++j) gload_lds16(s0[j], myA + (j << 9));
  }

  const u16* bp = Wp + (lane << 3);
  const int fr_row = ((lane & 15) << 6);            // frag row base (u16)
  const int pch0 = ((lane >> 4) ^ (lane & 7)) << 3; // ks=0 phys chunk (u16)
  const int pch1 = ((4 + (lane >> 4)) ^ (lane & 7)) << 3;

  // ---- main loop: k = 0..25, MFMA(k) + stage(k+1) ----
#pragma unroll 2
  for (int k = 0; k < 26; ++k) {
    const int p = k & 1;
    // 1. source addrs for tile k+1 (idv currently holds k+1 ids)
    const u16* sn[4];
#pragma unroll
    for (int j = 0; j < 4; ++j)
      sn[j] = (idv[j] >= 0) ? F + ((size_t)(unsigned)idv[j] << 6) + swz : zsrc;
    // 2. idv <- k+2 ids (nbrT padded to 28 rows; never consumed for k+2==27)
#pragma unroll
    for (int j = 0; j < 4; ++j) {
      const int v = vwave + (j << 3) + lrow;
      idv[j] = (v < N) ? nbrT[(size_t)(k + 2) * N + v] : -1;
    }
    // 3. B(k) fragments (L1-resident broadcast)
    bf16x8 bfr[2][4];
#pragma unroll
    for (int ks = 0; ks < 2; ++ks)
#pragma unroll
      for (int c = 0; c < 4; ++c)
        bfr[ks][c] = *reinterpret_cast<const bf16x8*>(bp + ((size_t)k << 12) + (ks << 11) + (c << 9));
    // 4. drain exactly tile(k)'s 4 gld_lds (idv+B stay in flight)
    asm volatile("s_waitcnt vmcnt(12)" ::: "memory");
    // 5. ds_read A-frags of tile k (swizzled; 2-way max bank aliasing = free)
    bf16x8 afr[2][2];
    {
      const u16* ab = myA + (p << 11);
#pragma unroll
      for (int m = 0; m < 2; ++m) {
        afr[m][0] = *reinterpret_cast<const bf16x8*>(ab + (m << 10) + fr_row + pch0);
        afr[m][1] = *reinterpret_cast<const bf16x8*>(ab + (m << 10) + fr_row + pch1);
      }
    }
    // 6. stage tile k+1 into the other buffer (lands during next iteration)
    {
      u16* nb = myA + ((p ^ 1) << 11);
#pragma unroll
      for (int j = 0; j < 4; ++j) gload_lds16(sn[j], nb + (j << 9));
    }
    // 7. MFMA (compiler inserts lgkmcnt for ds_reads + counted vmcnt for B)
#pragma unroll
    for (int m = 0; m < 2; ++m)
#pragma unroll
      for (int c = 0; c < 4; ++c)
        acc[m][c] = __builtin_amdgcn_mfma_f32_16x16x32_bf16(afr[m][0], bfr[0][c], acc[m][c], 0, 0, 0);
#pragma unroll
    for (int m = 0; m < 2; ++m)
#pragma unroll
      for (int c = 0; c < 4; ++c)
        acc[m][c] = __builtin_amdgcn_mfma_f32_16x16x32_bf16(afr[m][1], bfr[1][c], acc[m][c], 0, 0, 0);
  }

  // ---- epilogue: k = 26 (tile in buf 0, no prefetch) ----
  {
    bf16x8 bfr[2][4];
#pragma unroll
    for (int ks = 0; ks < 2; ++ks)
#pragma unroll
      for (int c = 0; c < 4; ++c)
        bfr[ks][c] = *reinterpret_cast<const bf16x8*>(bp + ((size_t)26 << 12) + (ks << 11) + (c << 9));
    asm volatile("s_waitcnt vmcnt(8)" ::: "memory");
    bf16x8 afr[2][2];
    const u16* ab = myA;  // 26&1 == 0
#pragma unroll
    for (int m = 0; m < 2; ++m) {
      afr[m][0] = *reinterpret_cast<const bf16x8*>(ab + (m << 10) + fr_row + pch0);
      afr[m][1] = *reinterpret_cast<const bf16x8*>(ab + (m << 10) + fr_row + pch1);
    }
#pragma unroll
    for (int m = 0; m < 2; ++m)
#pragma unroll
      for (int c = 0; c < 4; ++c)
        acc[m][c] = __builtin_amdgcn_mfma_f32_16x16x32_bf16(afr[m][0], bfr[0][c], acc[m][c], 0, 0, 0);
#pragma unroll
    for (int m = 0; m < 2; ++m)
#pragma unroll
      for (int c = 0; c < 4; ++c)
        acc[m][c] = __builtin_amdgcn_mfma_f32_16x16x32_bf16(afr[m][1], bfr[1][c], acc[m][c], 0, 0, 0);
  }

  // ---- store f32 + fused BN-stat partial reduction ----
  const int row0 = wg * 128 + (w << 5) + ((lane >> 4) << 2);
#pragma unroll
  for (int m = 0; m < 2; ++m) {
#pragma unroll
    for (int c = 0; c < 4; ++c) {
      const int col = (c << 4) + (lane & 15);
#pragma unroll
      for (int e = 0; e < 4; ++e) {
        const int v = row0 + (m << 4) + e;
        if (v < N) out[((size_t)v << 6) + col] = acc[m][c][e];
      }
    }
  }

#pragma unroll
  for (int c = 0; c < 4; ++c) {
    float s = 0.f, qq = 0.f;
#pragma unroll
    for (int m = 0; m < 2; ++m)
#pragma unroll
      for (int e = 0; e < 4; ++e) {
        const float x = acc[m][c][e];  // OOB rows contribute exact 0
        s += x;
        qq += x * x;
      }
    s += __shfl_xor(s, 16, 64);
    s += __shfl_xor(s, 32, 64);
    qq += __shfl_xor(qq, 16, 64);
    qq += __shfl_xor(qq, 32, 64);
    if (lane < 16) {
      sred[w][(c << 4) + lane] = s;
      sred[w][64 + (c << 4) + lane] = qq;
    }
  }
  __syncthreads();
  if (t < 128) {
    const float tot = sred[0][t] + sred[1][t] + sred[2][t] + sred[3][t];
    atomicAdd(&stats[t], tot);
  }
}

// ---------------- BN finalize / apply ----------------

__global__ void k_final(const float* __restrict__ stats, const float* __restrict__ gamma,
                        const float* __restrict__ beta, float* __restrict__ sb, int N) {
  const int c = threadIdx.x;  // 64
  const float inv = 1.0f / (float)N;
  const float mu = stats[c] * inv;
  const float var = stats[64 + c] * inv - mu * mu;
  const float sc = gamma[c] * rsqrtf(var + EPSBN);
  sb[c] = sc;
  sb[64 + c] = beta[c] - mu * sc;
}

// y = relu(x*sc+bi) -> bf16 x_net
__global__ void k_apply1(const float* __restrict__ x, const float* __restrict__ sb,
                         u16* __restrict__ xb, int n4) {
  int i = blockIdx.x * 256 + threadIdx.x;
  if (i >= n4) return;
  const int cg = i & 15;
  float4 v = reinterpret_cast<const float4*>(x)[i];
  const float4 sc = reinterpret_cast<const float4*>(sb)[cg];
  const float4 bi = reinterpret_cast<const float4*>(sb)[16 + cg];
  float y0 = fmaxf(0.f, v.x * sc.x + bi.x);
  float y1 = fmaxf(0.f, v.y * sc.y + bi.y);
  float y2 = fmaxf(0.f, v.z * sc.z + bi.z);
  float y3 = fmaxf(0.f, v.w * sc.w + bi.w);
  ushort4 o;
  o.x = f2bf(y0); o.y = f2bf(y1); o.z = f2bf(y2); o.w = f2bf(y3);
  reinterpret_cast<ushort4*>(xb)[i] = o;
}

// out = x_net + relu(x*sc+bi)   (in-place on conv2 raw output)
__global__ void k_apply2(float* __restrict__ io, const float* __restrict__ sb,
                         const u16* __restrict__ xb, int n4) {
  int i = blockIdx.x * 256 + threadIdx.x;
  if (i >= n4) return;
  const int cg = i & 15;
  float4 v = reinterpret_cast<const float4*>(io)[i];
  const float4 sc = reinterpret_cast<const float4*>(sb)[cg];
  const float4 bi = reinterpret_cast<const float4*>(sb)[16 + cg];
  const ushort4 xn = reinterpret_cast<const ushort4*>(xb)[i];
  float4 o;
  o.x = bf2f(xn.x) + fmaxf(0.f, v.x * sc.x + bi.x);
  o.y = bf2f(xn.y) + fmaxf(0.f, v.y * sc.y + bi.y);
  o.z = bf2f(xn.z) + fmaxf(0.f, v.z * sc.z + bi.z);
  o.w = bf2f(xn.w) + fmaxf(0.f, v.w * sc.w + bi.w);
  reinterpret_cast<float4*>(io)[i] = o;
}

// ---------------- host ----------------

extern "C" void kernel_launch(void* const* d_in, const int* in_sizes, int n_in,
                              void* d_out, int out_size, void* d_ws, size_t ws_size,
                              hipStream_t stream) {
  const float* feats = (const float*)d_in[0];
  const float* W1 = (const float*)d_in[1];
  const float* g1 = (const float*)d_in[2];
  const float* b1 = (const float*)d_in[3];
  const float* W2 = (const float*)d_in[4];
  const float* g2 = (const float*)d_in[5];
  const float* b2 = (const float*)d_in[6];
  const int* nbr = (const int*)d_in[7];
  const int N = in_sizes[0] / 64;

  char* ws = (char*)d_ws;
  size_t off = 0;
  auto alloc = [&](size_t bytes) {
    void* p = ws + off;
    off = (off + bytes + 255) & ~(size_t)255;
    return p;
  };
  u16* featsb = (u16*)alloc((size_t)N * 64 * 2);
  u16* xnetb = (u16*)alloc((size_t)N * 64 * 2);
  u16* w1p = (u16*)alloc((size_t)KOFF * 4096 * 2);
  u16* w2p = (u16*)alloc((size_t)KOFF * 4096 * 2);
  float* stats = (float*)alloc(256 * 4);  // [s1 q1 s2 q2] x 64
  float* sb1 = (float*)alloc(128 * 4);
  float* sb2 = (float*)alloc(128 * 4);
  float* zbuf = (float*)alloc(128);       // 128B zero-page for missing neighbors
  int* nbrT = (int*)alloc(((size_t)(KOFF + 1) * N + 256) * 4);  // padded: k+2 reads stay in-bounds
  float* outf = (float*)d_out;

  const int n4 = N * 16;
  const int gPrep = (n4 + 255) / 256;
  const int gW = (KOFF * 4096 + 255) / 256;
  const int gConv = (N + 127) / 128;

  k_prep_feats<<<gPrep, 256, 0, stream>>>(feats, featsb, stats, zbuf, n4);
  k_prep_w<<<gW, 256, 0, stream>>>(W1, w1p);
  k_prep_w<<<gW, 256, 0, stream>>>(W2, w2p);
  k_prep_nbrT<<<(N + 63) / 64, 256, 0, stream>>>(nbr, nbrT, N);

  k_conv<<<gConv, 256, 0, stream>>>(featsb, w1p, nbrT, (const u16*)zbuf, outf, stats, N);
  k_final<<<1, 64, 0, stream>>>(stats, g1, b1, sb1, N);
  k_apply1<<<gPrep, 256, 0, stream>>>(outf, sb1, xnetb, n4);

  k_conv<<<gConv, 256, 0, stream>>>(xnetb, w2p, nbrT, (const u16*)zbuf, outf, stats + 128, N);
  k_final<<<1, 64, 0, stream>>>(stats + 128, g2, b2, sb2, N);
  k_apply2<<<gPrep, 256, 0, stream>>>(outf, sb2, xnetb, n4);
}

// Round 6
// 325.123 us; speedup vs baseline: 1.0082x; 1.0082x over previous
//
#include <hip/hip_runtime.h>
#include <cstdint>
#include <cstddef>

typedef unsigned short u16;
typedef __bf16 bf16x8 __attribute__((ext_vector_type(8)));
typedef float f32x4 __attribute__((ext_vector_type(4)));

#define KOFF 27
#define EPSBN 1e-5f

__device__ inline u16 f2bf(float f) {
  unsigned int u = __float_as_uint(f);
  unsigned int r = (u + 0x7FFFu + ((u >> 16) & 1u)) >> 16;  // RNE
  return (u16)r;
}
__device__ inline float bf2f(u16 h) {
  return __uint_as_float(((unsigned int)h) << 16);
}

typedef const __attribute__((address_space(1))) void ga_void;
typedef __attribute__((address_space(3))) void lds_void;
__device__ __forceinline__ void gload_lds16(const void* g, void* l) {
  __builtin_amdgcn_global_load_lds((ga_void*)g, (lds_void*)l, 16, 0, 0);
}

// ---------------- prep kernels ----------------

// cast feats -> bf16; block 0 zeroes stats accumulators + the 128B zero-page
__global__ void k_prep_feats(const float* __restrict__ in, u16* __restrict__ out,
                             float* __restrict__ stats, float* __restrict__ zbuf, int n4) {
  if (blockIdx.x == 0) {
    stats[threadIdx.x] = 0.f;
    if (threadIdx.x < 32) zbuf[threadIdx.x] = 0.f;
  }
  int i = blockIdx.x * 256 + threadIdx.x;
  if (i >= n4) return;
  const float4 v = reinterpret_cast<const float4*>(in)[i];
  ushort4 o;
  o.x = f2bf(v.x); o.y = f2bf(v.y); o.z = f2bf(v.z); o.w = f2bf(v.w);
  reinterpret_cast<ushort4*>(out)[i] = o;
}

// Pack W[k][j][c] (27x64x64 f32) into per-lane MFMA B-fragment order (bf16):
// Wp[ k*4096 + ks*2048 + ct*512 + lane*8 + e ] = W[k][ ks*32 + (lane>>4)*8 + e ][ ct*16 + (lane&15) ]
__global__ void k_prep_w(const float* __restrict__ W, u16* __restrict__ Wp) {
  int tid = blockIdx.x * 256 + threadIdx.x;
  if (tid >= KOFF * 4096) return;
  int k = tid >> 12;
  int rem = tid & 4095;
  int slot = rem >> 3;
  int e = rem & 7;
  int ks = slot >> 8;
  int ct = (slot >> 6) & 3;
  int lane = slot & 63;
  int j = ks * 32 + ((lane >> 4) << 3) + e;
  int c = ct * 16 + (lane & 15);
  Wp[tid] = f2bf(W[(k * 64 + j) * 64 + c]);
}

// Transpose nbr [N,27] -> nbrT [27,N] via LDS tiles (coalesced both sides)
__global__ void k_prep_nbrT(const int* __restrict__ nbr, int* __restrict__ nbrT, int N) {
  __shared__ int L[64 * KOFF];
  const int t = threadIdx.x;
  const int v0 = blockIdx.x * 64;
  const int nv = min(64, N - v0);
  const int cnt = nv * KOFF;
  for (int i = t; i < cnt; i += 256) L[i] = nbr[(size_t)v0 * KOFF + i];
  __syncthreads();
  for (int i = t; i < KOFF * 64; i += 256) {
    int k = i >> 6, j = i & 63;
    if (j < nv) nbrT[(size_t)k * N + v0 + j] = L[j * KOFF + k];
  }
}

// ---------------- conv kernel ----------------
// Block 256 = 4 waves; each wave owns 64 voxels x all 64 output channels.
// B (8KB W[k], shared by all 4 waves) staged ONCE PER BLOCK into a shared LDS
// double-buffer via global_load_lds, consumed via conflict-free ds_read_b128 —
// removes ~75% of the per-CU vector-memory return traffic that bound R2-R5.
// Pipeline: per k, [stage B(k+1) first (sched_barrier-pinned oldest)] ...
// [counted s_waitcnt vmcnt(12) + raw s_barrier] — A/idv loads stay in flight
// across the barrier; vmcnt never drains to 0 in the loop.
// A: direct-to-register gather, zero-page address fallback (deterministic
// vmcnt count — no exec-mask branch games), refilled between MFMA half-clusters.
__launch_bounds__(256, 3)
__global__ void k_conv(const u16* __restrict__ F, const u16* __restrict__ Wp,
                       const int* __restrict__ nbrT, const u16* __restrict__ zbuf,
                       float* __restrict__ out, float* __restrict__ stats, int N) {
  __shared__ u16 Bs[2][4096];   // 16 KB B double-buffer
  __shared__ float sred[4][128];
  const int t = threadIdx.x;
  const int w = t >> 6;
  const int lane = t & 63;

  // bijective XCD-aware block swizzle (m204 form)
  const int nwg = gridDim.x, bid = blockIdx.x;
  const int q = nwg >> 3, r = nwg & 7;
  const int xcd = bid & 7, o = bid >> 3;
  const int wg = (xcd < r ? xcd * (q + 1) : r * (q + 1) + (xcd - r) * q) + o;

  const int vbase = wg * 256 + (w << 6) + (lane & 15);
  const int ch = (lane >> 4) << 3;  // A-frag channel offset (u16 units)
  const u16* zsrc = zbuf + ch;
  const char* Wpb = (const char*)Wp;
  char* BsB = (char*)Bs;

  f32x4 acc[4][4];
#pragma unroll
  for (int m = 0; m < 4; ++m)
#pragma unroll
    for (int c = 0; c < 4; ++c) acc[m][c] = (f32x4){0.f, 0.f, 0.f, 0.f};

  // ---- prologue ----
  bool vok[4];
  int idv[4];
#pragma unroll
  for (int m = 0; m < 4; ++m) {
    const int v = vbase + (m << 4);
    vok[m] = v < N;
    idv[m] = nbrT[min(v, N - 1)];
    idv[m] = vok[m] ? idv[m] : -1;  // k=0 ids
  }
  {  // stage B(0) -> Bs[0]
    const char* s = Wpb + (w << 10) + (lane << 4);
    char* d = BsB + (w << 10);
    gload_lds16(s, d);
    gload_lds16(s + 4096, d + 4096);
  }
  __builtin_amdgcn_sched_barrier(0);
  bf16x8 a0[4], a1[4];
#pragma unroll
  for (int m = 0; m < 4; ++m) {  // A(0) (compiler waits idv(0) for addresses)
    const u16* src = (idv[m] >= 0) ? F + ((size_t)(unsigned)idv[m] << 6) + ch : zsrc;
    a0[m] = *reinterpret_cast<const bf16x8*>(src);
    a1[m] = *reinterpret_cast<const bf16x8*>(src + 32);
  }
#pragma unroll
  for (int m = 0; m < 4; ++m) {  // idv <- k=1
    const int id_ = nbrT[(size_t)N + min(vbase + (m << 4), N - 1)];
    idv[m] = vok[m] ? id_ : -1;
  }
  asm volatile("s_waitcnt vmcnt(12)" ::: "memory");  // B(0) staged; A+idv in flight
  __builtin_amdgcn_s_barrier();

  // ---- main loop: k = 0..25 ----
#pragma unroll 2
  for (int k = 0; k < 26; ++k) {
    const int p = k & 1;
    {  // stage B(k+1) -> Bs[p^1]  (FIRST: must stay oldest for vmcnt(12))
      const char* s = Wpb + ((size_t)(k + 1) << 13) + (w << 10) + (lane << 4);
      char* d = BsB + ((p ^ 1) << 13) + (w << 10);
      gload_lds16(s, d);
      gload_lds16(s + 4096, d + 4096);
    }
    __builtin_amdgcn_sched_barrier(0);
    // B(k) fragments from LDS (contiguous 16B/lane -> conflict-free)
    bf16x8 bfr[2][4];
    {
      const u16* bb = Bs[p] + (lane << 3);
#pragma unroll
      for (int ks = 0; ks < 2; ++ks)
#pragma unroll
        for (int c = 0; c < 4; ++c)
          bfr[ks][c] = *reinterpret_cast<const bf16x8*>(bb + (ks << 11) + (c << 9));
    }
    // MFMA half-cluster ks=0 (consumes a0)
#pragma unroll
    for (int m = 0; m < 4; ++m)
#pragma unroll
      for (int c = 0; c < 4; ++c)
        acc[m][c] = __builtin_amdgcn_mfma_f32_16x16x32_bf16(a0[m], bfr[0][c], acc[m][c], 0, 0, 0);
    // refill a0 <- A(k+1) (idv holds k+1 ids; zero-page for missing)
    const u16* srcs[4];
#pragma unroll
    for (int m = 0; m < 4; ++m) {
      srcs[m] = (idv[m] >= 0) ? F + ((size_t)(unsigned)idv[m] << 6) + ch : zsrc;
      a0[m] = *reinterpret_cast<const bf16x8*>(srcs[m]);
    }
    // MFMA half-cluster ks=1 (consumes old a1)
#pragma unroll
    for (int m = 0; m < 4; ++m)
#pragma unroll
      for (int c = 0; c < 4; ++c)
        acc[m][c] = __builtin_amdgcn_mfma_f32_16x16x32_bf16(a1[m], bfr[1][c], acc[m][c], 0, 0, 0);
#pragma unroll
    for (int m = 0; m < 4; ++m)
      a1[m] = *reinterpret_cast<const bf16x8*>(srcs[m] + 32);
    {  // idv <- k+2 ids (row 27 is padding)
      const int* nk = nbrT + (size_t)(k + 2) * N;
#pragma unroll
      for (int m = 0; m < 4; ++m) {
        const int id_ = nk[min(vbase + (m << 4), N - 1)];
        idv[m] = vok[m] ? id_ : -1;
      }
    }
    // outstanding: [B 2][a0 4][a1 4][idv 4] = 14 -> waits only the 2 B stages
    asm volatile("s_waitcnt vmcnt(12)" ::: "memory");
    __builtin_amdgcn_s_barrier();
  }

  // ---- epilogue: k = 26 (B in Bs[0], A in a0/a1) ----
  {
    bf16x8 bfr[2][4];
    const u16* bb = Bs[0] + (lane << 3);
#pragma unroll
    for (int ks = 0; ks < 2; ++ks)
#pragma unroll
      for (int c = 0; c < 4; ++c)
        bfr[ks][c] = *reinterpret_cast<const bf16x8*>(bb + (ks << 11) + (c << 9));
#pragma unroll
    for (int m = 0; m < 4; ++m)
#pragma unroll
      for (int c = 0; c < 4; ++c)
        acc[m][c] = __builtin_amdgcn_mfma_f32_16x16x32_bf16(a0[m], bfr[0][c], acc[m][c], 0, 0, 0);
#pragma unroll
    for (int m = 0; m < 4; ++m)
#pragma unroll
      for (int c = 0; c < 4; ++c)
        acc[m][c] = __builtin_amdgcn_mfma_f32_16x16x32_bf16(a1[m], bfr[1][c], acc[m][c], 0, 0, 0);
  }

  // ---- store f32 + fused BN-stat partial reduction ----
  const int row0 = wg * 256 + (w << 6) + ((lane >> 4) << 2);
#pragma unroll
  for (int m = 0; m < 4; ++m) {
#pragma unroll
    for (int c = 0; c < 4; ++c) {
      const int col = (c << 4) + (lane & 15);
#pragma unroll
      for (int e = 0; e < 4; ++e) {
        const int v = row0 + (m << 4) + e;
        if (v < N) out[((size_t)v << 6) + col] = acc[m][c][e];
      }
    }
  }

#pragma unroll
  for (int c = 0; c < 4; ++c) {
    float s = 0.f, qq = 0.f;
#pragma unroll
    for (int m = 0; m < 4; ++m)
#pragma unroll
      for (int e = 0; e < 4; ++e) {
        const float x = acc[m][c][e];  // OOB rows contribute exact 0
        s += x;
        qq += x * x;
      }
    s += __shfl_xor(s, 16, 64);
    s += __shfl_xor(s, 32, 64);
    qq += __shfl_xor(qq, 16, 64);
    qq += __shfl_xor(qq, 32, 64);
    if (lane < 16) {
      sred[w][(c << 4) + lane] = s;
      sred[w][64 + (c << 4) + lane] = qq;
    }
  }
  __syncthreads();
  if (t < 128) {
    const float tot = sred[0][t] + sred[1][t] + sred[2][t] + sred[3][t];
    atomicAdd(&stats[t], tot);
  }
}

// ---------------- BN finalize / apply ----------------

__global__ void k_final(const float* __restrict__ stats, const float* __restrict__ gamma,
                        const float* __restrict__ beta, float* __restrict__ sb, int N) {
  const int c = threadIdx.x;  // 64
  const float inv = 1.0f / (float)N;
  const float mu = stats[c] * inv;
  const float var = stats[64 + c] * inv - mu * mu;
  const float sc = gamma[c] * rsqrtf(var + EPSBN);
  sb[c] = sc;
  sb[64 + c] = beta[c] - mu * sc;
}

// y = relu(x*sc+bi) -> bf16 x_net
__global__ void k_apply1(const float* __restrict__ x, const float* __restrict__ sb,
                         u16* __restrict__ xb, int n4) {
  int i = blockIdx.x * 256 + threadIdx.x;
  if (i >= n4) return;
  const int cg = i & 15;
  float4 v = reinterpret_cast<const float4*>(x)[i];
  const float4 sc = reinterpret_cast<const float4*>(sb)[cg];
  const float4 bi = reinterpret_cast<const float4*>(sb)[16 + cg];
  float y0 = fmaxf(0.f, v.x * sc.x + bi.x);
  float y1 = fmaxf(0.f, v.y * sc.y + bi.y);
  float y2 = fmaxf(0.f, v.z * sc.z + bi.z);
  float y3 = fmaxf(0.f, v.w * sc.w + bi.w);
  ushort4 o;
  o.x = f2bf(y0); o.y = f2bf(y1); o.z = f2bf(y2); o.w = f2bf(y3);
  reinterpret_cast<ushort4*>(xb)[i] = o;
}

// out = x_net + relu(x*sc+bi)   (in-place on conv2 raw output)
__global__ void k_apply2(float* __restrict__ io, const float* __restrict__ sb,
                         const u16* __restrict__ xb, int n4) {
  int i = blockIdx.x * 256 + threadIdx.x;
  if (i >= n4) return;
  const int cg = i & 15;
  float4 v = reinterpret_cast<const float4*>(io)[i];
  const float4 sc = reinterpret_cast<const float4*>(sb)[cg];
  const float4 bi = reinterpret_cast<const float4*>(sb)[16 + cg];
  const ushort4 xn = reinterpret_cast<const ushort4*>(xb)[i];
  float4 o;
  o.x = bf2f(xn.x) + fmaxf(0.f, v.x * sc.x + bi.x);
  o.y = bf2f(xn.y) + fmaxf(0.f, v.y * sc.y + bi.y);
  o.z = bf2f(xn.z) + fmaxf(0.f, v.z * sc.z + bi.z);
  o.w = bf2f(xn.w) + fmaxf(0.f, v.w * sc.w + bi.w);
  reinterpret_cast<float4*>(io)[i] = o;
}

// ---------------- host ----------------

extern "C" void kernel_launch(void* const* d_in, const int* in_sizes, int n_in,
                              void* d_out, int out_size, void* d_ws, size_t ws_size,
                              hipStream_t stream) {
  const float* feats = (const float*)d_in[0];
  const float* W1 = (const float*)d_in[1];
  const float* g1 = (const float*)d_in[2];
  const float* b1 = (const float*)d_in[3];
  const float* W2 = (const float*)d_in[4];
  const float* g2 = (const float*)d_in[5];
  const float* b2 = (const float*)d_in[6];
  const int* nbr = (const int*)d_in[7];
  const int N = in_sizes[0] / 64;

  char* ws = (char*)d_ws;
  size_t off = 0;
  auto alloc = [&](size_t bytes) {
    void* p = ws + off;
    off = (off + bytes + 255) & ~(size_t)255;
    return p;
  };
  u16* featsb = (u16*)alloc((size_t)N * 64 * 2);
  u16* xnetb = (u16*)alloc((size_t)N * 64 * 2);
  u16* w1p = (u16*)alloc((size_t)KOFF * 4096 * 2);
  u16* w2p = (u16*)alloc((size_t)KOFF * 4096 * 2);
  float* stats = (float*)alloc(256 * 4);  // [s1 q1 s2 q2] x 64
  float* sb1 = (float*)alloc(128 * 4);
  float* sb2 = (float*)alloc(128 * 4);
  float* zbuf = (float*)alloc(128);       // 128B zero-page for missing neighbors
  int* nbrT = (int*)alloc(((size_t)(KOFF + 1) * N + 256) * 4);  // +1 padding row
  float* outf = (float*)d_out;

  const int n4 = N * 16;
  const int gPrep = (n4 + 255) / 256;
  const int gW = (KOFF * 4096 + 255) / 256;
  const int gConv = (N + 255) / 256;

  k_prep_feats<<<gPrep, 256, 0, stream>>>(feats, featsb, stats, zbuf, n4);
  k_prep_w<<<gW, 256, 0, stream>>>(W1, w1p);
  k_prep_w<<<gW, 256, 0, stream>>>(W2, w2p);
  k_prep_nbrT<<<(N + 63) / 64, 256, 0, stream>>>(nbr, nbrT, N);

  k_conv<<<gConv, 256, 0, stream>>>(featsb, w1p, nbrT, (const u16*)zbuf, outf, stats, N);
  k_final<<<1, 64, 0, stream>>>(stats, g1, b1, sb1, N);
  k_apply1<<<gPrep, 256, 0, stream>>>(outf, sb1, xnetb, n4);

  k_conv<<<gConv, 256, 0, stream>>>(xnetb, w2p, nbrT, (const u16*)zbuf, outf, stats + 128, N);
  k_final<<<1, 64, 0, stream>>>(stats + 128, g2, b2, sb2, N);
  k_apply2<<<gPrep, 256, 0, stream>>>(outf, sb2, xnetb, n4);
}

// Round 7
// 292.661 us; speedup vs baseline: 1.1200x; 1.1109x over previous
//
#include <hip/hip_runtime.h>
#include <cstdint>
#include <cstddef>

typedef unsigned short u16;
typedef __bf16 bf16x8 __attribute__((ext_vector_type(8)));
typedef float f32x4 __attribute__((ext_vector_type(4)));

#define KOFF 27
#define EPSBN 1e-5f

__device__ inline u16 f2bf(float f) {
  unsigned int u = __float_as_uint(f);
  unsigned int r = (u + 0x7FFFu + ((u >> 16) & 1u)) >> 16;  // RNE
  return (u16)r;
}
__device__ inline float bf2f(u16 h) {
  return __uint_as_float(((unsigned int)h) << 16);
}

// ---------------- fused prep kernel ----------------
// blocks [0,G): pack neighbor table into per-wave int4 layout
//   nbrP[(k*G + g)*16 + l] = int4{ nbr[g*64+l][k], nbr[g*64+l+16][k],
//                                  nbr[g*64+l+32][k], nbr[g*64+l+48][k] }
//   plane k=27 = all -1 (padding for the k+2 prefetch).
// blocks [G, G+gW): pack W1 into MFMA B-frag order (bf16)
// blocks [G+gW, G+2gW): pack W2
// blocks [G+2gW, ...): cast feats->bf16 (first block also zeroes stats[256])
__global__ void k_prep(const float* __restrict__ feats, const float* __restrict__ W1,
                       const float* __restrict__ W2, const int* __restrict__ nbr,
                       u16* __restrict__ featsb, u16* __restrict__ w1p,
                       u16* __restrict__ w2p, int4* __restrict__ nbrP,
                       float* __restrict__ stats, int N, int G, int gW, int n4) {
  __shared__ int L[64 * KOFF];
  const int t = threadIdx.x;
  const int bid = blockIdx.x;

  if (bid < G) {  // neighbor pack
    const int g = bid;
    const int v0 = g * 64;
    for (int i = t; i < 64 * KOFF; i += 256) {
      const int v = v0 + i / KOFF;
      L[i] = (v < N) ? nbr[(size_t)v * KOFF + i % KOFF] : -1;
    }
    __syncthreads();
    for (int i = t; i < KOFF * 16; i += 256) {
      const int k = i >> 4, l = i & 15;
      int4 val;
      val.x = L[l * KOFF + k];
      val.y = L[(l + 16) * KOFF + k];
      val.z = L[(l + 32) * KOFF + k];
      val.w = L[(l + 48) * KOFF + k];
      nbrP[((size_t)k * G + g) * 16 + l] = val;
    }
    if (t < 16) nbrP[((size_t)KOFF * G + g) * 16 + t] = make_int4(-1, -1, -1, -1);
    return;
  }
  if (bid < G + 2 * gW) {  // weight pack
    const int wi = bid - G;
    const bool second = wi >= gW;
    const float* W = second ? W2 : W1;
    u16* Wp = second ? w2p : w1p;
    const int tid = (second ? wi - gW : wi) * 256 + t;
    if (tid >= KOFF * 4096) return;
    const int k = tid >> 12;
    const int rem = tid & 4095;
    const int slot = rem >> 3;
    const int e = rem & 7;
    const int ks = slot >> 8;
    const int ct = (slot >> 6) & 3;
    const int lane = slot & 63;
    const int j = ks * 32 + ((lane >> 4) << 3) + e;
    const int c = ct * 16 + (lane & 15);
    Wp[tid] = f2bf(W[(k * 64 + j) * 64 + c]);
    return;
  }
  // feats cast
  const int idx = bid - G - 2 * gW;
  if (idx == 0) stats[t] = 0.f;
  const int i = idx * 256 + t;
  if (i >= n4) return;
  const float4 v = reinterpret_cast<const float4*>(feats)[i];
  ushort4 o;
  o.x = f2bf(v.x); o.y = f2bf(v.y); o.z = f2bf(v.z); o.w = f2bf(v.w);
  reinterpret_cast<ushort4*>(featsb)[i] = o;
}

// ---------------- conv kernel (R2 structure + refill interleave) ----------------
// Block 256 = 4 waves; each wave owns 64 voxels (group g) x all 64 out channels.
// Barrier-free main loop. Per k: B(k) frag loads (global, L1-resident broadcast),
// MFMA half-cluster ks0 on a0, REFILL a0 <- A(k+1) (ids prefetched), MFMA ks1 on
// a1, refill a1, prefetch ids(k+2) as ONE dwordx4. A(k+1) loads get >=310 cyc of
// MFMA+issue to land instead of being consumed in-iteration (R2's exposed chain).
__launch_bounds__(256, 3)
__global__ void k_conv(const u16* __restrict__ F, const u16* __restrict__ Wp,
                       const int4* __restrict__ nbrP, float* __restrict__ out,
                       float* __restrict__ stats, int N, int G) {
  __shared__ float sred[4][128];
  const int t = threadIdx.x;
  const int w = t >> 6;
  const int lane = t & 63;

  // bijective XCD-aware block swizzle (m204 form)
  const int nwg = gridDim.x, bid = blockIdx.x;
  const int q = nwg >> 3, r = nwg & 7;
  const int xcd = bid & 7, o = bid >> 3;
  const int wg = (xcd < r ? xcd * (q + 1) : r * (q + 1) + (xcd - r) * q) + o;

  const int g = wg * 4 + w;              // this wave's 64-voxel group
  const int ch = (lane >> 4) << 3;       // A-frag channel offset (u16 units)
  const size_t G16 = (size_t)G * 16;     // int4 stride per k-plane
  const int4* nb = nbrP + (size_t)g * 16 + (lane & 15);

  f32x4 acc[4][4];
#pragma unroll
  for (int m = 0; m < 4; ++m)
#pragma unroll
    for (int c = 0; c < 4; ++c) acc[m][c] = (f32x4){0.f, 0.f, 0.f, 0.f};

  // ---- prologue: A(0), ids(1) ----
  int4 idv = nb[0];
  bf16x8 a0[4], a1[4];
  {
    const int ids[4] = {idv.x, idv.y, idv.z, idv.w};
#pragma unroll
    for (int m = 0; m < 4; ++m) {
      a0[m] = (bf16x8){};
      a1[m] = (bf16x8){};
      if (ids[m] >= 0) {
        const u16* fr = F + ((size_t)(unsigned)ids[m] << 6) + ch;
        a0[m] = *reinterpret_cast<const bf16x8*>(fr);
        a1[m] = *reinterpret_cast<const bf16x8*>(fr + 32);
      }
    }
  }
  idv = nb[G16];  // ids for k=1

  const u16* bp = Wp + (lane << 3);

  // ---- main loop: k = 0..25 ----
#pragma unroll 2
  for (int k = 0; k < 26; ++k) {
    // B(k) fragments (all 4 waves read same 8KB -> L1 hits)
    bf16x8 bfr[2][4];
    {
      const u16* bk = bp + ((size_t)k << 12);
#pragma unroll
      for (int ks = 0; ks < 2; ++ks)
#pragma unroll
        for (int c = 0; c < 4; ++c)
          bfr[ks][c] = *reinterpret_cast<const bf16x8*>(bk + (ks << 11) + (c << 9));
    }
    const int ids[4] = {idv.x, idv.y, idv.z, idv.w};
    // MFMA half-cluster ks=0 (consumes a0 of k)
    __builtin_amdgcn_s_setprio(1);
#pragma unroll
    for (int m = 0; m < 4; ++m)
#pragma unroll
      for (int c = 0; c < 4; ++c)
        acc[m][c] = __builtin_amdgcn_mfma_f32_16x16x32_bf16(a0[m], bfr[0][c], acc[m][c], 0, 0, 0);
    __builtin_amdgcn_s_setprio(0);
    // refill a0 <- A(k+1) low half
#pragma unroll
    for (int m = 0; m < 4; ++m) {
      bf16x8 v = (bf16x8){};
      if (ids[m] >= 0)
        v = *reinterpret_cast<const bf16x8*>(F + ((size_t)(unsigned)ids[m] << 6) + ch);
      a0[m] = v;
    }
    // MFMA half-cluster ks=1 (consumes a1 of k)
    __builtin_amdgcn_s_setprio(1);
#pragma unroll
    for (int m = 0; m < 4; ++m)
#pragma unroll
      for (int c = 0; c < 4; ++c)
        acc[m][c] = __builtin_amdgcn_mfma_f32_16x16x32_bf16(a1[m], bfr[1][c], acc[m][c], 0, 0, 0);
    __builtin_amdgcn_s_setprio(0);
    // refill a1 <- A(k+1) high half
#pragma unroll
    for (int m = 0; m < 4; ++m) {
      bf16x8 v = (bf16x8){};
      if (ids[m] >= 0)
        v = *reinterpret_cast<const bf16x8*>(F + ((size_t)(unsigned)ids[m] << 6) + ch + 32);
      a1[m] = v;
    }
    // ids(k+2): single dwordx4 (plane 27 = -1 padding)
    idv = nb[(size_t)(k + 2) * G16];
  }

  // ---- epilogue: k = 26 ----
  {
    bf16x8 bfr[2][4];
    const u16* bk = bp + ((size_t)26 << 12);
#pragma unroll
    for (int ks = 0; ks < 2; ++ks)
#pragma unroll
      for (int c = 0; c < 4; ++c)
        bfr[ks][c] = *reinterpret_cast<const bf16x8*>(bk + (ks << 11) + (c << 9));
    __builtin_amdgcn_s_setprio(1);
#pragma unroll
    for (int m = 0; m < 4; ++m)
#pragma unroll
      for (int c = 0; c < 4; ++c)
        acc[m][c] = __builtin_amdgcn_mfma_f32_16x16x32_bf16(a0[m], bfr[0][c], acc[m][c], 0, 0, 0);
#pragma unroll
    for (int m = 0; m < 4; ++m)
#pragma unroll
      for (int c = 0; c < 4; ++c)
        acc[m][c] = __builtin_amdgcn_mfma_f32_16x16x32_bf16(a1[m], bfr[1][c], acc[m][c], 0, 0, 0);
    __builtin_amdgcn_s_setprio(0);
  }

  // ---- store f32 + fused BN-stat partial reduction ----
  const int row0 = g * 64 + ((lane >> 4) << 2);
#pragma unroll
  for (int m = 0; m < 4; ++m) {
#pragma unroll
    for (int c = 0; c < 4; ++c) {
      const int col = (c << 4) + (lane & 15);
#pragma unroll
      for (int e = 0; e < 4; ++e) {
        const int v = row0 + (m << 4) + e;
        if (v < N) out[((size_t)v << 6) + col] = acc[m][c][e];
      }
    }
  }

#pragma unroll
  for (int c = 0; c < 4; ++c) {
    float s = 0.f, qq = 0.f;
#pragma unroll
    for (int m = 0; m < 4; ++m)
#pragma unroll
      for (int e = 0; e < 4; ++e) {
        const float x = acc[m][c][e];  // OOB rows contribute exact 0
        s += x;
        qq += x * x;
      }
    s += __shfl_xor(s, 16, 64);
    s += __shfl_xor(s, 32, 64);
    qq += __shfl_xor(qq, 16, 64);
    qq += __shfl_xor(qq, 32, 64);
    if (lane < 16) {
      sred[w][(c << 4) + lane] = s;
      sred[w][64 + (c << 4) + lane] = qq;
    }
  }
  __syncthreads();
  if (t < 128) {
    const float tot = sred[0][t] + sred[1][t] + sred[2][t] + sred[3][t];
    atomicAdd(&stats[t], tot);
  }
}

// ---------------- BN finalize / apply ----------------

__global__ void k_final(const float* __restrict__ stats, const float* __restrict__ gamma,
                        const float* __restrict__ beta, float* __restrict__ sb, int N) {
  const int c = threadIdx.x;  // 64
  const float inv = 1.0f / (float)N;
  const float mu = stats[c] * inv;
  const float var = stats[64 + c] * inv - mu * mu;
  const float sc = gamma[c] * rsqrtf(var + EPSBN);
  sb[c] = sc;
  sb[64 + c] = beta[c] - mu * sc;
}

// y = relu(x*sc+bi) -> bf16 x_net
__global__ void k_apply1(const float* __restrict__ x, const float* __restrict__ sb,
                         u16* __restrict__ xb, int n4) {
  int i = blockIdx.x * 256 + threadIdx.x;
  if (i >= n4) return;
  const int cg = i & 15;
  float4 v = reinterpret_cast<const float4*>(x)[i];
  const float4 sc = reinterpret_cast<const float4*>(sb)[cg];
  const float4 bi = reinterpret_cast<const float4*>(sb)[16 + cg];
  float y0 = fmaxf(0.f, v.x * sc.x + bi.x);
  float y1 = fmaxf(0.f, v.y * sc.y + bi.y);
  float y2 = fmaxf(0.f, v.z * sc.z + bi.z);
  float y3 = fmaxf(0.f, v.w * sc.w + bi.w);
  ushort4 o;
  o.x = f2bf(y0); o.y = f2bf(y1); o.z = f2bf(y2); o.w = f2bf(y3);
  reinterpret_cast<ushort4*>(xb)[i] = o;
}

// out = x_net + relu(x*sc+bi)   (in-place on conv2 raw output)
__global__ void k_apply2(float* __restrict__ io, const float* __restrict__ sb,
                         const u16* __restrict__ xb, int n4) {
  int i = blockIdx.x * 256 + threadIdx.x;
  if (i >= n4) return;
  const int cg = i & 15;
  float4 v = reinterpret_cast<const float4*>(io)[i];
  const float4 sc = reinterpret_cast<const float4*>(sb)[cg];
  const float4 bi = reinterpret_cast<const float4*>(sb)[16 + cg];
  const ushort4 xn = reinterpret_cast<const ushort4*>(xb)[i];
  float4 o;
  o.x = bf2f(xn.x) + fmaxf(0.f, v.x * sc.x + bi.x);
  o.y = bf2f(xn.y) + fmaxf(0.f, v.y * sc.y + bi.y);
  o.z = bf2f(xn.z) + fmaxf(0.f, v.z * sc.z + bi.z);
  o.w = bf2f(xn.w) + fmaxf(0.f, v.w * sc.w + bi.w);
  reinterpret_cast<float4*>(io)[i] = o;
}

// ---------------- host ----------------

extern "C" void kernel_launch(void* const* d_in, const int* in_sizes, int n_in,
                              void* d_out, int out_size, void* d_ws, size_t ws_size,
                              hipStream_t stream) {
  const float* feats = (const float*)d_in[0];
  const float* W1 = (const float*)d_in[1];
  const float* g1 = (const float*)d_in[2];
  const float* b1 = (const float*)d_in[3];
  const float* W2 = (const float*)d_in[4];
  const float* g2 = (const float*)d_in[5];
  const float* b2 = (const float*)d_in[6];
  const int* nbr = (const int*)d_in[7];
  const int N = in_sizes[0] / 64;
  const int G = (N + 63) / 64;  // 64-voxel groups

  char* ws = (char*)d_ws;
  size_t off = 0;
  auto alloc = [&](size_t bytes) {
    void* p = ws + off;
    off = (off + bytes + 255) & ~(size_t)255;
    return p;
  };
  u16* featsb = (u16*)alloc((size_t)N * 64 * 2);
  u16* xnetb = (u16*)alloc((size_t)N * 64 * 2);
  u16* w1p = (u16*)alloc((size_t)KOFF * 4096 * 2);
  u16* w2p = (u16*)alloc((size_t)KOFF * 4096 * 2);
  float* stats = (float*)alloc(256 * 4);  // [s1 q1 s2 q2] x 64
  float* sb1 = (float*)alloc(128 * 4);
  float* sb2 = (float*)alloc(128 * 4);
  int4* nbrP = (int4*)alloc((size_t)(KOFF + 1) * G * 16 * 16);
  float* outf = (float*)d_out;

  const int n4 = N * 16;
  const int gPrep = (n4 + 255) / 256;
  const int gW = (KOFF * 4096 + 255) / 256;
  const int gConv = (G + 3) / 4;

  k_prep<<<G + 2 * gW + gPrep, 256, 0, stream>>>(feats, W1, W2, nbr, featsb, w1p, w2p,
                                                 nbrP, stats, N, G, gW, n4);

  k_conv<<<gConv, 256, 0, stream>>>(featsb, w1p, nbrP, outf, stats, N, G);
  k_final<<<1, 64, 0, stream>>>(stats, g1, b1, sb1, N);
  k_apply1<<<gPrep, 256, 0, stream>>>(outf, sb1, xnetb, n4);

  k_conv<<<gConv, 256, 0, stream>>>(xnetb, w2p, nbrP, outf, stats + 128, N, G);
  k_final<<<1, 64, 0, stream>>>(stats + 128, g2, b2, sb2, N);
  k_apply2<<<gPrep, 256, 0, stream>>>(outf, sb2, xnetb, n4);
}